// Round 2
// baseline (192.414 us; speedup 1.0000x reference)
//
#include <hip/hip_runtime.h>
#include <hip/hip_bf16.h>

// LUTLayerBasic: out[b] = sum_d W[d*16 + ch(b,d)], ch = 4 sign bits of gathered x.
// R2: one-hot bf16 MFMA GEMM with NO LDS staging in the K-loop.
//  - B fragments: register-double-buffered global_load_dwordx4 from pre-permuted
//    bf16 W (wf), L2-resident per XCD via bijective XCD-grouping block swizzle.
//  - A fragments: one-hot rows fetched from a 640 B LDS identity LUT, indexed by
//    packed channel bytes read directly from global (L1-resident slice).
//  - No __syncthreads in the K-loop; split-K handled by f32 HW atomics into a
//    memset-zeroed output (order-dependent f32 rounding ok vs threshold).
//
// Dims: B=2048, N_IN=2048, D=1024, A=4, O=2048, C=16, K=N_LUT=16384.

typedef __attribute__((ext_vector_type(8))) short short8;
typedef __attribute__((ext_vector_type(4))) float f32x4;

__device__ __forceinline__ bool anchors_is_i64(const int* a) {
  int v = 0;
#pragma unroll
  for (int i = 0; i < 32; ++i) v |= a[2 * i + 1];
  return v == 0;
}

__device__ __forceinline__ int ld_anchor(const int* a, int i, bool is64) {
  return is64 ? a[2 * i] : a[i];
}

__device__ __forceinline__ unsigned f2bf(float f) {  // RNE f32 -> bf16
  unsigned u = __float_as_uint(f);
  return ((u + 0x7fffu + ((u >> 16) & 1u)) >> 16) & 0xffffu;
}

// ---------------------------------------------------------------------------
// Kernel 1: packed channels. chp[t][b] = ch(b,2t) | ch(b,2t+1)<<8, t in [0,512)
// ---------------------------------------------------------------------------
__global__ __launch_bounds__(256) void k_channels(const float* __restrict__ x,
                                                  const int* __restrict__ anc,
                                                  unsigned short* __restrict__ chp) {
  const int b = blockIdx.x * 256 + threadIdx.x;  // gridDim.x = 8
  const int t = blockIdx.y;                      // [0, 512)
  const bool is64 = anchors_is_i64(anc);
  unsigned ch0 = 0, ch1 = 0;
#pragma unroll
  for (int i = 0; i < 4; ++i) {
    int a0 = ld_anchor(anc, (2 * t) * 4 + i, is64);
    int a1 = ld_anchor(anc, (2 * t + 1) * 4 + i, is64);
    ch0 |= (x[(size_t)b * 2048 + a0] > 0.0f ? 1u : 0u) << i;
    ch1 |= (x[(size_t)b * 2048 + a1] > 0.0f ? 1u : 0u) << i;
  }
  chp[(size_t)t * 2048 + b] = (unsigned short)(ch0 | (ch1 << 8));
}

// ---------------------------------------------------------------------------
// Kernel 2: W (f32 [16384][2048]) -> bf16 fragment-linear chunks:
//   chunk ((kt*128 + nc)*64 + l) is 16 B holding
//   W[kt*32 + kmap(l>>4, j)][nc*16 + (l&15)], kmap(q,j)=q*4+(j&3)+16*(j>>2).
// ---------------------------------------------------------------------------
__global__ __launch_bounds__(256) void k_wfrag(const float* __restrict__ W,
                                               uint4* __restrict__ wf) {
  const unsigned flat = blockIdx.x * 256 + threadIdx.x;  // [0, 4194304)
  const unsigned l = flat & 63u, nc = (flat >> 6) & 127u, kt = flat >> 13;
  const unsigned q = l >> 4, col = nc * 16 + (l & 15);
  unsigned hs[8];
#pragma unroll
  for (int j = 0; j < 8; ++j) {
    unsigned k = kt * 32 + q * 4 + (j & 3) + ((j >> 2) << 4);
    hs[j] = f2bf(W[(size_t)k * 2048 + col]);
  }
  uint4 o;
  o.x = hs[0] | (hs[1] << 16);
  o.y = hs[2] | (hs[3] << 16);
  o.z = hs[4] | (hs[5] << 16);
  o.w = hs[6] | (hs[7] << 16);
  wf[flat] = o;
}

// ---------------------------------------------------------------------------
// Kernel 3: one-hot GEMM, no-LDS-staging K-loop. Tile 128x128, 4 waves 2x2,
// wave tile 64x64, BK=32, split-K KP=4 via atomics. Grid = 1024 blocks.
// ---------------------------------------------------------------------------
__global__ __launch_bounds__(256, 4) void k_gemm(const uint4* __restrict__ wf,
                                                 const unsigned short* __restrict__ chp,
                                                 float* __restrict__ out) {
  constexpr int NSTEPS = 128;  // K-steps per kp slice (512 / KP), KP = 4
  __shared__ __align__(8) unsigned short lut[320];  // 16 entries x 20 u16 (40 B)

  const int tid = threadIdx.x, lane = tid & 63;
  const int w = tid >> 6, wm = w >> 1, wn = w & 1;

  // XCD-grouping swizzle (1024 = 8 XCD x 128): all 16 mBlk's of a (nBlk,kp)
  // W-panel land on one XCD -> 2 MiB panel stays L2-resident.
  const unsigned orig = blockIdx.x;
  const unsigned xcd = orig & 7u, slot = orig >> 3;
  const unsigned pl = slot >> 4, mBlk = slot & 15u;
  const unsigned panel = xcd * 8u + pl;        // [0, 64)
  const unsigned nBlk = panel & 15u, kp = panel >> 4;
  const int k0 = (int)kp * NSTEPS;

  for (int i = tid; i < 320; i += 256) {
    int c = i / 20, h = i % 20;
    lut[i] = (h == c) ? (unsigned short)0x3F80 : (unsigned short)0;
  }
  __syncthreads();

  const uint4* wB = wf + ((size_t)(unsigned)k0 * 128u + nBlk * 8u + (unsigned)wn * 4u) * 64u + lane;
  const unsigned short* cp = chp + (size_t)(unsigned)k0 * 2048u + mBlk * 128u +
                             (unsigned)wm * 64u + (unsigned)(lane & 15);

  f32x4 acc[4][4];
#pragma unroll
  for (int a = 0; a < 4; ++a)
#pragma unroll
    for (int b = 0; b < 4; ++b) acc[a][b] = f32x4{0.f, 0.f, 0.f, 0.f};

  short8 bA[4], bB[4];
  unsigned short hA[4], hB[4];
  const char* lb = (const char*)lut;
  const unsigned q8 = (unsigned)((lane >> 4) & 3) * 8u;

#define LOADB(dst, s)                                                    \
  _Pragma("unroll") for (int nf = 0; nf < 4; ++nf)                       \
      dst[nf] = *(const short8*)(wB + (size_t)(s)*8192 + nf * 64);
#define LOADC(dst, s)                                                    \
  _Pragma("unroll") for (int mi = 0; mi < 4; ++mi)                       \
      dst[mi] = cp[(size_t)(s)*2048 + mi * 16];
#define STEP(bf, hv)                                                     \
  _Pragma("unroll") for (int mi = 0; mi < 4; ++mi) {                     \
    unsigned pk = hv[mi];                                                \
    uint2 lo = *(const uint2*)(lb + (pk & 0xffu) * 40u + q8);            \
    uint2 hi = *(const uint2*)(lb + (pk >> 8) * 40u + q8);               \
    union { short8 v; unsigned u[4]; } af;                               \
    af.u[0] = lo.x; af.u[1] = lo.y; af.u[2] = hi.x; af.u[3] = hi.y;      \
    _Pragma("unroll") for (int nf = 0; nf < 4; ++nf)                     \
      acc[mi][nf] = __builtin_amdgcn_mfma_f32_16x16x32_bf16(             \
          af.v, bf[nf], acc[mi][nf], 0, 0, 0);                           \
  }

  LOADB(bA, 0) LOADC(hA, 0)
  LOADB(bB, 1) LOADC(hB, 1)

  int step = 0;
  for (; step + 2 < NSTEPS; step += 2) {
    STEP(bA, hA)
    LOADB(bA, step + 2) LOADC(hA, step + 2)
    STEP(bB, hB)
    LOADB(bB, step + 3) LOADC(hB, step + 3)
  }
  STEP(bA, hA)
  STEP(bB, hB)
#undef LOADB
#undef LOADC
#undef STEP

  const int row0 = (int)mBlk * 128 + wm * 64;
  const int col0 = (int)nBlk * 128 + wn * 64;
  const int rsub = ((lane >> 4) & 3) * 4;
  const int csub = lane & 15;
#pragma unroll
  for (int mi = 0; mi < 4; ++mi)
#pragma unroll
    for (int nf = 0; nf < 4; ++nf) {
      int r = row0 + mi * 16 + rsub;
      int c = col0 + nf * 16 + csub;
#pragma unroll
      for (int j = 0; j < 4; ++j)
        unsafeAtomicAdd(&out[(size_t)(r + j) * 2048 + c], acc[mi][nf][j]);
    }
}

// ---------------------------------------------------------------------------
// Fallback (ws too small): direct gather row-sum, one block per sample.
// ---------------------------------------------------------------------------
__global__ __launch_bounds__(256) void k_direct(const float* __restrict__ x,
                                                const int* __restrict__ anc,
                                                const float* __restrict__ W,
                                                float* __restrict__ out) {
  __shared__ unsigned rowoff[1024];
  const int b = blockIdx.x;
  const bool is64 = anchors_is_i64(anc);
  for (int d = threadIdx.x; d < 1024; d += 256) {
    unsigned ch = 0;
#pragma unroll
    for (int i = 0; i < 4; ++i) {
      int a = ld_anchor(anc, d * 4 + i, is64);
      ch |= (x[(size_t)b * 2048 + a] > 0.0f ? 1u : 0u) << i;
    }
    rowoff[d] = (unsigned)(d * 16 + ch) * 2048u;
  }
  __syncthreads();
  f32x4 a0 = {0.f, 0.f, 0.f, 0.f}, a1 = {0.f, 0.f, 0.f, 0.f};
  const int o0 = threadIdx.x * 4, o1 = 1024 + threadIdx.x * 4;
  for (int d = 0; d < 1024; ++d) {
    unsigned ro = rowoff[d];
    a0 += *(const f32x4*)(W + ro + o0);
    a1 += *(const f32x4*)(W + ro + o1);
  }
  *(f32x4*)(out + (size_t)b * 2048 + o0) = a0;
  *(f32x4*)(out + (size_t)b * 2048 + o1) = a1;
}

// ---------------------------------------------------------------------------
extern "C" void kernel_launch(void* const* d_in, const int* in_sizes, int n_in,
                              void* d_out, int out_size, void* d_ws, size_t ws_size,
                              hipStream_t stream) {
  const float* x = (const float*)d_in[0];
  const int* anc = (const int*)d_in[1];
  const float* W = (const float*)d_in[2];
  float* out = (float*)d_out;

  const size_t CHP_BYTES = 2ull * 1024 * 1024;  // 512 x 2048 u16
  const size_t WF_BYTES = 64ull * 1024 * 1024;  // 4M x 16 B
  const size_t BASE = CHP_BYTES + WF_BYTES;     // 66 MiB

  if (ws_size < BASE) {
    k_direct<<<2048, 256, 0, stream>>>(x, anc, W, out);
    return;
  }

  unsigned short* chp = (unsigned short*)d_ws;
  uint4* wf = (uint4*)((char*)d_ws + CHP_BYTES);

  hipMemsetAsync(d_out, 0, (size_t)out_size * sizeof(float), stream);
  k_channels<<<dim3(8, 512), 256, 0, stream>>>(x, anc, chp);
  k_wfrag<<<16384, 256, 0, stream>>>(W, wf);
  k_gemm<<<1024, 256, 0, stream>>>(wf, chp, out);
}